// Round 10
// baseline (506.649 us; speedup 1.0000x reference)
//
#include <hip/hip_runtime.h>
#include <hip/hip_fp16.h>
#include <math.h>

#define IN_F 64
#define OUT_F 32
#define NEG_SLOPE 0.2f

#define BK_SHIFT 7
#define BK_SIZE 128          // nodes per coarse bucket
#define NB2MAX 1024          // max buckets (N <= 131072)
#define NBLKA 256            // edge-pass block count

__device__ __forceinline__ float leaky(float v) {
    return (v > 0.0f) ? v : NEG_SLOPE * v;
}

// Fused: blocks [0, PB) projection GEMM; blocks [PB, PB+NBLKA) coarse totals.
__global__ __launch_bounds__(256) void k_projhist(
        const float* __restrict__ x, const float* __restrict__ W,
        const float* __restrict__ att_src, const float* __restrict__ att_dst,
        __half2* __restrict__ h2, float* __restrict__ asrc, float* __restrict__ adst,
        const int* __restrict__ dst, int* __restrict__ totals,
        int N, int NB2, int E, int epb, int PB) {
    __shared__ int smem[2560];               // 10 KB, overlaid per role
    const int tid = threadIdx.x;

    if (blockIdx.x >= PB) {
        // ---- coarse totals role: LDS hist + one global atomic per bucket ----
        int* lh = smem;
        const int blk = blockIdx.x - PB;
        for (int i = tid; i < NB2; i += 256) lh[i] = 0;
        __syncthreads();
        const int e0 = blk * epb, e1 = min(E, e0 + epb);
        for (int e = e0 + tid; e < e1; e += 256) atomicAdd(&lh[dst[e] >> BK_SHIFT], 1);
        __syncthreads();
        for (int b = tid; b < NB2; b += 256)
            if (lh[b]) atomicAdd(&totals[b], lh[b]);
        return;
    }

    // ---- projection role: h = x @ W (8 nodes/block), logits ----
    float* Ws = (float*)smem;                // 2048 floats
    float* xs = Ws + IN_F * OUT_F;           // 512 floats
    for (int i = tid; i < IN_F * OUT_F; i += 256) Ws[i] = W[i];
    const int base = blockIdx.x * 8;
    for (int i = tid; i < 8 * IN_F; i += 256) {
        int node = base + i / IN_F;
        xs[i] = (node < N) ? x[(size_t)base * IN_F + i] : 0.0f;
    }
    __syncthreads();

    const int ln = tid >> 5;
    const int c  = tid & 31;
    const int node = base + ln;
    float sum = 0.0f;
    #pragma unroll
    for (int k = 0; k < IN_F; ++k) sum += xs[ln * IN_F + k] * Ws[k * OUT_F + c];

    float s1 = __shfl_xor(sum, 1);
    if (node < N) {
        if ((c & 1) == 0) {
            __half2 hv;
            hv.x = __float2half_rn(sum);
            hv.y = __float2half_rn(s1);
            h2[(size_t)node * 16 + (c >> 1)] = hv;
        }
        float vs = sum * att_src[c];
        float vd = sum * att_dst[c];
        #pragma unroll
        for (int m = 16; m >= 1; m >>= 1) {
            vs += __shfl_xor(vs, m);
            vd += __shfl_xor(vd, m);
        }
        if (c == 0) {
            asrc[node] = vs;
            adst[node] = vd;
        }
    }
}

// Single-block exclusive scan of bucket totals (nb <= 1024) -> bbase + gcur.
__global__ __launch_bounds__(1024) void k_scan(const int* __restrict__ totals,
                                               int* __restrict__ bbase,
                                               int* __restrict__ gcur, int nb, int E) {
    const int tid = threadIdx.x;             // 1024
    int v = (tid < nb) ? totals[tid] : 0;
    const int orig = v;
    const int lane = tid & 63;
    #pragma unroll
    for (int m = 1; m < 64; m <<= 1) {
        int u = __shfl_up(v, m);
        if (lane >= m) v += u;
    }
    __shared__ int wt[16];
    if (lane == 63) wt[tid >> 6] = v;
    __syncthreads();
    if (tid < 64) {
        int w = (tid < 16) ? wt[tid] : 0;
        #pragma unroll
        for (int m = 1; m < 16; m <<= 1) {
            int u = __shfl_up(w, m);
            if (tid >= m) w += u;
        }
        if (tid < 16) wt[tid] = w;           // inclusive wave totals
    }
    __syncthreads();
    if (tid >= 64) v += wt[(tid >> 6) - 1];
    const int excl = v - orig;
    if (tid < nb) {
        bbase[tid] = excl;
        gcur[tid]  = excl;
    }
    if (tid == 0) bbase[nb] = E;
}

// Partition: two local passes. (1) LDS count; (2) reserve a contiguous run per
// bucket via one global atomicAdd; (3) place packed records (d&127)<<17 | s.
__global__ __launch_bounds__(512) void k_bpart(const int* __restrict__ src,
                                               const int* __restrict__ dst,
                                               int* __restrict__ gcur,
                                               int* __restrict__ recs,
                                               int NB2, int E, int epb) {
    __shared__ int lh[NB2MAX];
    const int tid = threadIdx.x, blk = blockIdx.x;   // 512 threads
    for (int b = tid; b < NB2; b += 512) lh[b] = 0;
    __syncthreads();
    const int e0 = blk * epb, e1 = min(E, e0 + epb);
    for (int e = e0 + tid; e < e1; e += 512) atomicAdd(&lh[dst[e] >> BK_SHIFT], 1);
    __syncthreads();
    for (int b = tid; b < NB2; b += 512) {
        int cbk = lh[b];
        lh[b] = cbk ? atomicAdd(&gcur[b], cbk) : 0;  // run base (block-private)
    }
    __syncthreads();
    for (int e = e0 + tid; e < e1; e += 512) {       // range is L2-hot (2nd pass)
        int s = src[e];
        int d = dst[e];
        int p = atomicAdd(&lh[d >> BK_SHIFT], 1);    // LDS cursor
        recs[p] = ((d & (BK_SIZE - 1)) << 17) | s;
    }
}

// Fused bucket gather: one block per 128-node bucket. LDS accumulators
// (32 ch + denom per node), stream the bucket's recs (coarse order suffices),
// 16 lanes per record (half2 per lane) -> 16 records per 256-thr iteration,
// unroll 2 -> 8 random h2 lines in flight per wave. Epilogue fuses self-loop,
// bias, relu; contiguous out writes.
__global__ __launch_bounds__(256) void k_bgather(
        const int* __restrict__ recs, const int* __restrict__ bbase,
        const float* __restrict__ asrc, const float* __restrict__ adst,
        const __half2* __restrict__ h2, const float* __restrict__ bias,
        float* __restrict__ out, int N) {
    __shared__ float s_acc[BK_SIZE * 33];    // [dl*33 + c], c=32 is denom l
    __shared__ float s_adst[BK_SIZE];
    const int b = blockIdx.x, tid = threadIdx.x;
    const int nb0 = b << BK_SHIFT;
    for (int i = tid; i < BK_SIZE * 33; i += 256) s_acc[i] = 0.0f;
    for (int i = tid; i < BK_SIZE; i += 256) {
        int n = nb0 + i;
        s_adst[i] = (n < N) ? adst[n] : 0.0f;
    }
    __syncthreads();
    const int cb0 = bbase[b], cb1 = bbase[b + 1];
    const int count = cb1 - cb0;
    const int slot = tid >> 4;               // 0..15 (4 records per wave)
    const int c2   = tid & 15;               // half2 channel pair
    #pragma unroll 2
    for (int i0 = 0; i0 < count; i0 += 16) {
        int i = i0 + slot;
        if (i < count) {
            int r  = recs[cb0 + i];          // broadcast across 16 lanes
            int s  = r & 0x1FFFF;
            int dl = r >> 17;
            float p = __expf(leaky(asrc[s] + s_adst[dl]));
            float2 hv = __half22float2(h2[(size_t)s * 16 + c2]);
            atomicAdd(&s_acc[dl * 33 + 2 * c2],     p * hv.x);
            atomicAdd(&s_acc[dl * 33 + 2 * c2 + 1], p * hv.y);
            if (c2 == 0) atomicAdd(&s_acc[dl * 33 + 32], p);
        }
    }
    __syncthreads();
    const int c = tid & 31;
    const float bc = bias[c];
    for (int nl = tid >> 5; nl < BK_SIZE; nl += 8) {
        int n = nb0 + nl;
        if (n >= N) break;
        float pself = __expf(leaky(asrc[n] + s_adst[nl]));
        float hc = __half2float(((const __half*)h2)[(size_t)n * 32 + c]);
        float l = s_acc[nl * 33 + 32] + pself;
        float v = (s_acc[nl * 33 + c] + pself * hc) / l + bc;
        out[(size_t)n * 32 + c] = fmaxf(v, 0.0f);
    }
}

extern "C" void kernel_launch(void* const* d_in, const int* in_sizes, int n_in,
                              void* d_out, int out_size, void* d_ws, size_t ws_size,
                              hipStream_t stream) {
    const float* x        = (const float*)d_in[0];
    const int*   eidx     = (const int*)d_in[1];   // [2, E] flat int32
    const float* W        = (const float*)d_in[2];
    const float* att_src  = (const float*)d_in[3];
    const float* att_dst  = (const float*)d_in[4];
    const float* bias     = (const float*)d_in[5];
    float* out = (float*)d_out;

    const int N = in_sizes[0] / IN_F;
    const int E = in_sizes[1] / 2;
    const int* src = eidx;
    const int* dst = eidx + E;

    const int NB2 = (N + BK_SIZE - 1) >> BK_SHIFT;   // 782 buckets
    const int epb = (E + NBLKA - 1) / NBLKA;         // edges per hist/bpart block

    // Workspace (4 B elems, ~13.7 MB)
    int* u = (int*)d_ws;
    __half2* h2     = (__half2*)u;                   // N*16 half2 (N*16 ints)
    float*   asrc   = (float*)(u + (size_t)N * 16);  // N
    float*   adst   = asrc + N;                      // N
    int*     totals = (int*)(adst + N);              // NB2MAX
    int*     bbase  = totals + NB2MAX;               // NB2MAX + 1
    int*     gcur   = bbase + NB2MAX + 1;            // NB2MAX
    int*     recs   = gcur + NB2MAX;                 // E

    const int PB = (N + 7) / 8;                      // proj blocks in fused kernel

    hipMemsetAsync(totals, 0, (size_t)NB2 * sizeof(int), stream);

    k_projhist<<<PB + NBLKA, 256, 0, stream>>>(x, W, att_src, att_dst, h2, asrc, adst,
                                               dst, totals, N, NB2, E, epb, PB);
    k_scan<<<1, 1024, 0, stream>>>(totals, bbase, gcur, NB2, E);
    k_bpart<<<NBLKA, 512, 0, stream>>>(src, dst, gcur, recs, NB2, E, epb);
    k_bgather<<<NB2, 256, 0, stream>>>(recs, bbase, asrc, adst, h2, bias, out, N);
}

// Round 12
// 192.138 us; speedup vs baseline: 2.6369x; 2.6369x over previous
//
#include <hip/hip_runtime.h>
#include <hip/hip_fp16.h>
#include <math.h>

#define IN_F 64
#define OUT_F 32
#define NEG_SLOPE 0.2f

#define BK_SHIFT 7
#define BK 128           // nodes per bucket
#define NBMAX 1024       // max buckets (N <= 131072)
#define NBLKA 256        // edge-pass block count (= per-bucket scan width)
#define PSTAGE 10        // k_place register staging (mean count ~2046 < 2560)

__device__ __forceinline__ float leaky(float v) {
    return (v > 0.0f) ? v : NEG_SLOPE * v;
}

// Inclusive block scan, 256 threads. wsum: >=4-int LDS scratch.
__device__ __forceinline__ int incScan256(int v, int tid, int* wsum) {
    const int lane = tid & 63, wid = tid >> 6;
    #pragma unroll
    for (int m = 1; m < 64; m <<= 1) {
        int u = __shfl_up(v, m);
        if (lane >= m) v += u;
    }
    if (lane == 63) wsum[wid] = v;
    __syncthreads();
    int add = 0;
    for (int k = 0; k < wid; ++k) add += wsum[k];
    __syncthreads();
    return v + add;
}

// Inclusive block scan, 512 threads. wsum: >=8-int LDS scratch.
__device__ __forceinline__ int incScan512(int v, int tid, int* wsum) {
    const int lane = tid & 63, wid = tid >> 6;
    #pragma unroll
    for (int m = 1; m < 64; m <<= 1) {
        int u = __shfl_up(v, m);
        if (lane >= m) v += u;
    }
    if (lane == 63) wsum[wid] = v;
    __syncthreads();
    int add = 0;
    for (int k = 0; k < wid; ++k) add += wsum[k];
    __syncthreads();
    return v + add;
}

// Fused: blocks [0, PB) projection GEMM; blocks [PB, PB+NBLKA) coarse hist.
__global__ __launch_bounds__(256) void k_projhist(
        const float* __restrict__ x, const float* __restrict__ W,
        const float* __restrict__ att_src, const float* __restrict__ att_dst,
        __half2* __restrict__ h2, float* __restrict__ asrc, float* __restrict__ adst,
        const int* __restrict__ dst, int* __restrict__ hist,
        int N, int NB, int E, int epb, int PB) {
    __shared__ int smem[2560];               // 10 KB, overlaid per role
    const int tid = threadIdx.x;

    if (blockIdx.x >= PB) {
        // ---- coarse histogram role: hist[b*NBLKA + blk] ----
        int* lh = smem;
        const int blk = blockIdx.x - PB;
        for (int i = tid; i < NB; i += 256) lh[i] = 0;
        __syncthreads();
        const int e0 = blk * epb, e1 = min(E, e0 + epb);
        for (int e = e0 + tid; e < e1; e += 256) atomicAdd(&lh[dst[e] >> BK_SHIFT], 1);
        __syncthreads();
        for (int b = tid; b < NB; b += 256) hist[(size_t)b * NBLKA + blk] = lh[b];
        return;
    }

    // ---- projection role: h = x @ W (8 nodes/block), logits ----
    float* Ws = (float*)smem;                // 2048 floats
    float* xs = Ws + IN_F * OUT_F;           // 512 floats
    for (int i = tid; i < IN_F * OUT_F; i += 256) Ws[i] = W[i];
    const int base = blockIdx.x * 8;
    for (int i = tid; i < 8 * IN_F; i += 256) {
        int node = base + (i >> 6);
        xs[i] = (node < N) ? x[(size_t)base * IN_F + i] : 0.0f;
    }
    __syncthreads();

    const int ln = tid >> 5;
    const int c  = tid & 31;
    const int node = base + ln;
    float sum = 0.0f;
    #pragma unroll
    for (int k = 0; k < IN_F; ++k) sum += xs[ln * IN_F + k] * Ws[k * OUT_F + c];

    float s1 = __shfl_xor(sum, 1);
    if (node < N) {
        if ((c & 1) == 0) {
            __half2 hv;
            hv.x = __float2half_rn(sum);
            hv.y = __float2half_rn(s1);
            h2[(size_t)node * 16 + (c >> 1)] = hv;
        }
        float vs = sum * att_src[c];
        float vd = sum * att_dst[c];
        #pragma unroll
        for (int m = 16; m >= 1; m >>= 1) {
            vs += __shfl_xor(vs, m);
            vd += __shfl_xor(vd, m);
        }
        if (c == 0) {
            asrc[node] = vs;
            adst[node] = vd;
        }
    }
}

// Scan 1: one block per bucket; exclusive scan of hist[b][0..NBLKA) in place,
// bucket total -> bsum[b]. Coalesced (tid indexes blk).
__global__ __launch_bounds__(256) void k_scan1(int* __restrict__ hist,
                                               int* __restrict__ bsum, int NB) {
    __shared__ int wsum[4];
    const int b = blockIdx.x, tid = threadIdx.x;
    int v = hist[(size_t)b * NBLKA + tid];
    const int inc = incScan256(v, tid, wsum);
    hist[(size_t)b * NBLKA + tid] = inc - v;
    if (tid == 255) bsum[b] = inc;
}

// Pass B: 512 threads/block. Locally scan bucket totals -> bbase (LDS), seed
// per-bucket cursors with hist-run-base + bbase, place packed records
// (d&127)<<17 | s into block-private runs.
__global__ __launch_bounds__(512) void k_bpart(const int* __restrict__ src,
                                               const int* __restrict__ dst,
                                               const int* __restrict__ hist,
                                               const int* __restrict__ bsum,
                                               int* __restrict__ recs,
                                               int NB, int E, int epb) {
    __shared__ int tt[NBMAX];
    __shared__ int lcur[NBMAX];
    __shared__ int wsum[8];
    const int tid = threadIdx.x, blk = blockIdx.x;
    // load totals (padded with 0) and exclusive-scan in LDS: tt[b] = bbase[b]
    for (int i = tid; i < NBMAX; i += 512) tt[i] = (i < NB) ? bsum[i] : 0;
    __syncthreads();
    {
        int a0 = tt[tid * 2], a1 = tt[tid * 2 + 1];
        int s = a0 + a1;
        int inc = incScan512(s, tid, wsum);
        int run = inc - s;
        tt[tid * 2] = run; run += a0;
        tt[tid * 2 + 1] = run;
    }
    __syncthreads();
    for (int b = tid; b < NB; b += 512)
        lcur[b] = hist[(size_t)b * NBLKA + blk] + tt[b];
    __syncthreads();
    const int e0 = blk * epb, e1 = min(E, e0 + epb);
    for (int e = e0 + tid; e < e1; e += 512) {
        int s = src[e];
        int d = dst[e];
        int p = atomicAdd(&lcur[d >> BK_SHIFT], 1);   // LDS cursor, block-private
        recs[p] = ((d & (BK - 1)) << 17) | s;
    }
}

// Pass C: one block per bucket (128 nodes). Local bbase scan for cb0/cb1,
// register-staged records, fine 128-node histogram + scan, emit cnt/offs,
// place col into a contiguous window.
__global__ __launch_bounds__(256) void k_place(const int* __restrict__ recs,
                                               const int* __restrict__ bsum,
                                               int* __restrict__ cnt,
                                               int* __restrict__ offs,
                                               int* __restrict__ col,
                                               int NB, int E, int N) {
    __shared__ int tt[NBMAX];
    __shared__ int fineCnt[BK];
    __shared__ int cur[BK];
    __shared__ int wsum[4];
    const int b = blockIdx.x, tid = threadIdx.x;
    for (int i = tid; i < NBMAX; i += 256) tt[i] = (i < NB) ? bsum[i] : 0;
    __syncthreads();
    {
        int a0 = tt[tid * 4], a1 = tt[tid * 4 + 1], a2 = tt[tid * 4 + 2], a3 = tt[tid * 4 + 3];
        int s = a0 + a1 + a2 + a3;
        int inc = incScan256(s, tid, wsum);
        int run = inc - s;
        tt[tid * 4] = run;     run += a0;
        tt[tid * 4 + 1] = run; run += a1;
        tt[tid * 4 + 2] = run; run += a2;
        tt[tid * 4 + 3] = run;
    }
    __syncthreads();
    const int cb0 = tt[b];
    const int cb1 = (b + 1 < NB) ? tt[b + 1] : E;
    const int count = cb1 - cb0;
    int myrec[PSTAGE];
    if (tid < BK) fineCnt[tid] = 0;
    __syncthreads();
    #pragma unroll
    for (int k = 0; k < PSTAGE; ++k) {
        int i = tid + k * 256;
        if (i < count) {
            int v = recs[cb0 + i];
            myrec[k] = v;
            atomicAdd(&fineCnt[v >> 17], 1);
        }
    }
    for (int i = tid + PSTAGE * 256; i < count; i += 256)   // statistically never
        atomicAdd(&fineCnt[recs[cb0 + i] >> 17], 1);
    __syncthreads();
    const int v0 = (tid < BK) ? fineCnt[tid] : 0;
    const int inc = incScan256(v0, tid, wsum);
    const int excl = inc - v0;
    if (tid < BK) {
        const int node = (b << BK_SHIFT) + tid;
        if (node < N) {
            cnt[node]  = v0;
            offs[node] = cb0 + excl;
        }
        cur[tid] = cb0 + excl;
    }
    __syncthreads();
    #pragma unroll
    for (int k = 0; k < PSTAGE; ++k) {
        int i = tid + k * 256;
        if (i < count) {
            int r = myrec[k];
            int p = atomicAdd(&cur[r >> 17], 1);
            col[p] = r & 0x1FFFF;
        }
    }
    for (int i = tid + PSTAGE * 256; i < count; i += 256) {
        int r = recs[cb0 + i];
        int p = atomicAdd(&cur[r >> 17], 1);
        col[p] = r & 0x1FFFF;
    }
}

// Gather: one wave per node, 4 groups x 16 lanes (half2 channel pair).
// Each group takes a contiguous quarter; ALL edges go through the predicated
// 4-chunk (clamped indices, p=0 for masked lanes) -> no serial scalar tail.
__global__ void k_gather(const int* __restrict__ col, const int* __restrict__ offs,
                         const int* __restrict__ cnt, const float* __restrict__ asrc,
                         const float* __restrict__ adst, const __half2* __restrict__ h2,
                         const float* __restrict__ bias, float* __restrict__ out, int N) {
    int t = blockIdx.x * 256 + threadIdx.x;
    int n = t >> 6;
    if (n >= N) return;
    const int lane = t & 63;
    const int g  = lane >> 4;    // edge group 0..3
    const int c2 = lane & 15;    // half2 channel pair
    const float adst_n = adst[n];
    float l = 0.0f, accx = 0.0f, accy = 0.0f;
    if (g == 0) {                // self loop
        float p = __expf(leaky(asrc[n] + adst_n));
        float2 hv = __half22float2(h2[(size_t)n * 16 + c2]);
        l = p; accx = p * hv.x; accy = p * hv.y;
    }
    const int off = offs[n];
    const int deg = cnt[n];
    const int q = (deg + 3) >> 2;            // quarter size
    int j = off + g * q;
    const int jend = min(j + q, off + deg);
    for (; j < jend; j += 4) {
        const int last = jend - 1;
        int i1 = min(j + 1, last), i2 = min(j + 2, last), i3 = min(j + 3, last);
        int s0 = col[j], s1 = col[i1], s2 = col[i2], s3 = col[i3];
        float a0 = asrc[s0], a1 = asrc[s1], a2 = asrc[s2], a3 = asrc[s3];
        float2 h0 = __half22float2(h2[(size_t)s0 * 16 + c2]);
        float2 h1 = __half22float2(h2[(size_t)s1 * 16 + c2]);
        float2 hv2 = __half22float2(h2[(size_t)s2 * 16 + c2]);
        float2 h3 = __half22float2(h2[(size_t)s3 * 16 + c2]);
        float p0 = __expf(leaky(a0 + adst_n));
        float p1 = (j + 1 < jend) ? __expf(leaky(a1 + adst_n)) : 0.0f;
        float p2 = (j + 2 < jend) ? __expf(leaky(a2 + adst_n)) : 0.0f;
        float p3 = (j + 3 < jend) ? __expf(leaky(a3 + adst_n)) : 0.0f;
        l += (p0 + p1) + (p2 + p3);
        accx += p0 * h0.x + p1 * h1.x + p2 * hv2.x + p3 * h3.x;
        accy += p0 * h0.y + p1 * h1.y + p2 * hv2.y + p3 * h3.y;
    }
    l    += __shfl_xor(l, 16);    l    += __shfl_xor(l, 32);
    accx += __shfl_xor(accx, 16); accx += __shfl_xor(accx, 32);
    accy += __shfl_xor(accy, 16); accy += __shfl_xor(accy, 32);
    if (g == 0) {
        float inv = 1.0f / l;
        float2 bb = ((const float2*)bias)[c2];
        float2 o;
        o.x = fmaxf(accx * inv + bb.x, 0.0f);
        o.y = fmaxf(accy * inv + bb.y, 0.0f);
        ((float2*)out)[(size_t)n * 16 + c2] = o;
    }
}

extern "C" void kernel_launch(void* const* d_in, const int* in_sizes, int n_in,
                              void* d_out, int out_size, void* d_ws, size_t ws_size,
                              hipStream_t stream) {
    const float* x        = (const float*)d_in[0];
    const int*   eidx     = (const int*)d_in[1];   // [2, E] flat int32
    const float* W        = (const float*)d_in[2];
    const float* att_src  = (const float*)d_in[3];
    const float* att_dst  = (const float*)d_in[4];
    const float* bias     = (const float*)d_in[5];
    float* out = (float*)d_out;

    const int N = in_sizes[0] / IN_F;
    const int E = in_sizes[1] / 2;
    const int* src = eidx;
    const int* dst = eidx + E;

    const int NB  = (N + BK - 1) >> BK_SHIFT;    // 782 buckets
    const int epb = (E + NBLKA - 1) / NBLKA;     // edges per hist/bpart block

    // Workspace (4 B elems, ~21.9 MB)
    int* u = (int*)d_ws;
    size_t o = 0;
    __half2* h2   = (__half2*)(u + o); o += (size_t)N * 16;   // N*16 half2
    float*   asrc = (float*)(u + o);   o += N;
    float*   adst = (float*)(u + o);   o += N;
    int*     cnt  = u + o;             o += N;
    int*     offs = u + o;             o += N;
    int*     hist = u + o;             o += (size_t)NB * NBLKA;  // ~200k
    int*     bsum = u + o;             o += NBMAX;
    int*     col  = u + o;             o += E;
    int*     recs = u + o;             o += E;

    const int PB = (N + 7) / 8;                  // proj blocks in fused kernel
    const int gatherBlocks = ((size_t)N * 64 + 255) / 256;

    k_projhist<<<PB + NBLKA, 256, 0, stream>>>(x, W, att_src, att_dst, h2, asrc, adst,
                                               dst, hist, N, NB, E, epb, PB);
    k_scan1<<<NB, 256, 0, stream>>>(hist, bsum, NB);
    k_bpart<<<NBLKA, 512, 0, stream>>>(src, dst, hist, bsum, recs, NB, E, epb);
    k_place<<<NB, 256, 0, stream>>>(recs, bsum, cnt, offs, col, NB, E, N);
    k_gather<<<gatherBlocks, 256, 0, stream>>>(col, offs, cnt, asrc, adst, h2, bias, out, N);
}

// Round 13
// 169.287 us; speedup vs baseline: 2.9928x; 1.1350x over previous
//
#include <hip/hip_runtime.h>
#include <hip/hip_fp16.h>
#include <math.h>

#define IN_F 64
#define OUT_F 32
#define NEG_SLOPE 0.2f

#define BK_SHIFT 7
#define BK 128           // nodes per bucket
#define NBMAX 1024       // max buckets (N <= 131072)
#define NBLKA 256        // edge-pass block count (= per-bucket scan width)
#define PSTAGE 10        // k_place register staging (mean count ~2046 < 2560)

typedef _Float16 half8_t __attribute__((ext_vector_type(8)));
typedef float float4_t __attribute__((ext_vector_type(4)));

__device__ __forceinline__ float leaky(float v) {
    return (v > 0.0f) ? v : NEG_SLOPE * v;
}

// Inclusive block scan, 256 threads. wsum: >=4-int LDS scratch.
__device__ __forceinline__ int incScan256(int v, int tid, int* wsum) {
    const int lane = tid & 63, wid = tid >> 6;
    #pragma unroll
    for (int m = 1; m < 64; m <<= 1) {
        int u = __shfl_up(v, m);
        if (lane >= m) v += u;
    }
    if (lane == 63) wsum[wid] = v;
    __syncthreads();
    int add = 0;
    for (int k = 0; k < wid; ++k) add += wsum[k];
    __syncthreads();
    return v + add;
}

// Inclusive block scan, 512 threads. wsum: >=8-int LDS scratch.
__device__ __forceinline__ int incScan512(int v, int tid, int* wsum) {
    const int lane = tid & 63, wid = tid >> 6;
    #pragma unroll
    for (int m = 1; m < 64; m <<= 1) {
        int u = __shfl_up(v, m);
        if (lane >= m) v += u;
    }
    if (lane == 63) wsum[wid] = v;
    __syncthreads();
    int add = 0;
    for (int k = 0; k < wid; ++k) add += wsum[k];
    __syncthreads();
    return v + add;
}

// Fused: blocks [0, PB) MFMA projection (16 nodes/wave, 64/block, no LDS);
// blocks [PB, PB+NBLKA) coarse histogram (LDS).
// MFMA layouts (HW-verified, cdna_hip_programming.md §3 / m89/m120):
//   A[m=lane&15][k=(lane>>4)*8+j]   B[n=lane&15][k=(lane>>4)*8+j]
//   C/D: col(n)=lane&15, row(m)=(lane>>4)*4+reg
__global__ __launch_bounds__(256) void k_projhist(
        const float* __restrict__ x, const float* __restrict__ W,
        const float* __restrict__ att_src, const float* __restrict__ att_dst,
        __half2* __restrict__ h2, float* __restrict__ asrc, float* __restrict__ adst,
        const int* __restrict__ dst, int* __restrict__ hist,
        int N, int NB, int E, int epb, int PB) {
    __shared__ int smem[2560];               // 10 KB (hist role only)
    const int tid = threadIdx.x;

    if (blockIdx.x >= PB) {
        // ---- coarse histogram role: hist[b*NBLKA + blk] ----
        int* lh = smem;
        const int blk = blockIdx.x - PB;
        for (int i = tid; i < NB; i += 256) lh[i] = 0;
        __syncthreads();
        const int e0 = blk * epb, e1 = min(E, e0 + epb);
        for (int e = e0 + tid; e < e1; e += 256) atomicAdd(&lh[dst[e] >> BK_SHIFT], 1);
        __syncthreads();
        for (int b = tid; b < NB; b += 256) hist[(size_t)b * NBLKA + blk] = lh[b];
        return;
    }

    // ---- MFMA projection role ----
    const int wv   = tid >> 6;               // wave 0..3
    const int lane = tid & 63;
    const int m    = lane & 15;              // node-in-16 (A) / channel-in-group (B, C/D)
    const int quad = lane >> 4;              // 0..3
    const int node0 = (blockIdx.x * 4 + wv) * 16;
    if (node0 >= N) return;

    const int kb = quad * 8;
    // B fragments (W is 64x32, row-major W[k*32+c]); built once, L2-hot.
    half8_t b00, b01, b10, b11;
    #pragma unroll
    for (int j = 0; j < 8; ++j) {
        b00[j] = (_Float16)W[(kb + j) * OUT_F + m];
        b01[j] = (_Float16)W[(32 + kb + j) * OUT_F + m];
        b10[j] = (_Float16)W[(kb + j) * OUT_F + 16 + m];
        b11[j] = (_Float16)W[(32 + kb + j) * OUT_F + 16 + m];
    }
    // A fragments: x row (clamped in the tail block), 2x float4 per K-chunk.
    const int row = min(node0 + m, N - 1);
    const float* xr = x + (size_t)row * IN_F + kb;
    float4_t xa = *(const float4_t*)(xr);
    float4_t xb = *(const float4_t*)(xr + 4);
    float4_t xc = *(const float4_t*)(xr + 32);
    float4_t xd = *(const float4_t*)(xr + 36);
    half8_t a0, a1;
    #pragma unroll
    for (int j = 0; j < 4; ++j) {
        a0[j] = (_Float16)xa[j]; a0[4 + j] = (_Float16)xb[j];
        a1[j] = (_Float16)xc[j]; a1[4 + j] = (_Float16)xd[j];
    }
    float4_t acc0 = {0.f, 0.f, 0.f, 0.f};
    float4_t acc1 = {0.f, 0.f, 0.f, 0.f};
    acc0 = __builtin_amdgcn_mfma_f32_16x16x32_f16(a0, b00, acc0, 0, 0, 0);
    acc0 = __builtin_amdgcn_mfma_f32_16x16x32_f16(a1, b01, acc0, 0, 0, 0);
    acc1 = __builtin_amdgcn_mfma_f32_16x16x32_f16(a0, b10, acc1, 0, 0, 0);
    acc1 = __builtin_amdgcn_mfma_f32_16x16x32_f16(a1, b11, acc1, 0, 0, 0);

    // Epilogue: h2 (fp16 pairs) + asrc/adst per node.
    const float aS0 = att_src[m], aS1 = att_src[16 + m];
    const float aD0 = att_dst[m], aD1 = att_dst[16 + m];
    #pragma unroll
    for (int r = 0; r < 4; ++r) {
        const int node = node0 + quad * 4 + r;
        float h0 = acc0[r], h1 = acc1[r];
        float h0p = __shfl_xor(h0, 1);
        float h1p = __shfl_xor(h1, 1);
        if (node < N && (m & 1) == 0) {
            __half2 hv;
            hv.x = __float2half_rn(h0); hv.y = __float2half_rn(h0p);
            h2[(size_t)node * 16 + (m >> 1)] = hv;
            __half2 hw;
            hw.x = __float2half_rn(h1); hw.y = __float2half_rn(h1p);
            h2[(size_t)node * 16 + 8 + (m >> 1)] = hw;
        }
        float vs = h0 * aS0 + h1 * aS1;
        float vd = h0 * aD0 + h1 * aD1;
        #pragma unroll
        for (int mm = 1; mm < 16; mm <<= 1) {
            vs += __shfl_xor(vs, mm);
            vd += __shfl_xor(vd, mm);
        }
        if (node < N && m == 0) {
            asrc[node] = vs;
            adst[node] = vd;
        }
    }
}

// Scan 1: one block per bucket; exclusive scan of hist[b][0..NBLKA) in place,
// bucket total -> bsum[b].
__global__ __launch_bounds__(256) void k_scan1(int* __restrict__ hist,
                                               int* __restrict__ bsum, int NB) {
    __shared__ int wsum[4];
    const int b = blockIdx.x, tid = threadIdx.x;
    int v = hist[(size_t)b * NBLKA + tid];
    const int inc = incScan256(v, tid, wsum);
    hist[(size_t)b * NBLKA + tid] = inc - v;
    if (tid == 255) bsum[b] = inc;
}

// Pass B: 512 threads/block. Locally scan bucket totals -> bbase (LDS), seed
// per-bucket cursors, place packed records (d&127)<<17 | s into private runs.
__global__ __launch_bounds__(512) void k_bpart(const int* __restrict__ src,
                                               const int* __restrict__ dst,
                                               const int* __restrict__ hist,
                                               const int* __restrict__ bsum,
                                               int* __restrict__ recs,
                                               int NB, int E, int epb) {
    __shared__ int tt[NBMAX];
    __shared__ int lcur[NBMAX];
    __shared__ int wsum[8];
    const int tid = threadIdx.x, blk = blockIdx.x;
    for (int i = tid; i < NBMAX; i += 512) tt[i] = (i < NB) ? bsum[i] : 0;
    __syncthreads();
    {
        int a0 = tt[tid * 2], a1 = tt[tid * 2 + 1];
        int s = a0 + a1;
        int inc = incScan512(s, tid, wsum);
        int run = inc - s;
        tt[tid * 2] = run; run += a0;
        tt[tid * 2 + 1] = run;
    }
    __syncthreads();
    for (int b = tid; b < NB; b += 512)
        lcur[b] = hist[(size_t)b * NBLKA + blk] + tt[b];
    __syncthreads();
    const int e0 = blk * epb, e1 = min(E, e0 + epb);
    for (int e = e0 + tid; e < e1; e += 512) {
        int s = src[e];
        int d = dst[e];
        int p = atomicAdd(&lcur[d >> BK_SHIFT], 1);   // LDS cursor, block-private
        recs[p] = ((d & (BK - 1)) << 17) | s;
    }
}

// Pass C: one block per bucket (128 nodes). Local bbase scan for cb0/cb1,
// register-staged records, fine histogram + scan, emit cnt/offs, place col.
__global__ __launch_bounds__(256) void k_place(const int* __restrict__ recs,
                                               const int* __restrict__ bsum,
                                               int* __restrict__ cnt,
                                               int* __restrict__ offs,
                                               int* __restrict__ col,
                                               int NB, int E, int N) {
    __shared__ int tt[NBMAX];
    __shared__ int fineCnt[BK];
    __shared__ int cur[BK];
    __shared__ int wsum[4];
    const int b = blockIdx.x, tid = threadIdx.x;
    for (int i = tid; i < NBMAX; i += 256) tt[i] = (i < NB) ? bsum[i] : 0;
    __syncthreads();
    {
        int a0 = tt[tid * 4], a1 = tt[tid * 4 + 1], a2 = tt[tid * 4 + 2], a3 = tt[tid * 4 + 3];
        int s = a0 + a1 + a2 + a3;
        int inc = incScan256(s, tid, wsum);
        int run = inc - s;
        tt[tid * 4] = run;     run += a0;
        tt[tid * 4 + 1] = run; run += a1;
        tt[tid * 4 + 2] = run; run += a2;
        tt[tid * 4 + 3] = run;
    }
    __syncthreads();
    const int cb0 = tt[b];
    const int cb1 = (b + 1 < NB) ? tt[b + 1] : E;
    const int count = cb1 - cb0;
    int myrec[PSTAGE];
    if (tid < BK) fineCnt[tid] = 0;
    __syncthreads();
    #pragma unroll
    for (int k = 0; k < PSTAGE; ++k) {
        int i = tid + k * 256;
        if (i < count) {
            int v = recs[cb0 + i];
            myrec[k] = v;
            atomicAdd(&fineCnt[v >> 17], 1);
        }
    }
    for (int i = tid + PSTAGE * 256; i < count; i += 256)   // statistically never
        atomicAdd(&fineCnt[recs[cb0 + i] >> 17], 1);
    __syncthreads();
    const int v0 = (tid < BK) ? fineCnt[tid] : 0;
    const int inc = incScan256(v0, tid, wsum);
    const int excl = inc - v0;
    if (tid < BK) {
        const int node = (b << BK_SHIFT) + tid;
        if (node < N) {
            cnt[node]  = v0;
            offs[node] = cb0 + excl;
        }
        cur[tid] = cb0 + excl;
    }
    __syncthreads();
    #pragma unroll
    for (int k = 0; k < PSTAGE; ++k) {
        int i = tid + k * 256;
        if (i < count) {
            int r = myrec[k];
            int p = atomicAdd(&cur[r >> 17], 1);
            col[p] = r & 0x1FFFF;
        }
    }
    for (int i = tid + PSTAGE * 256; i < count; i += 256) {
        int r = recs[cb0 + i];
        int p = atomicAdd(&cur[r >> 17], 1);
        col[p] = r & 0x1FFFF;
    }
}

// Gather: one wave per node, 4 groups x 16 lanes (half2 channel pair).
// Predicated 4-chunks over a contiguous quarter per group; no scalar tail.
__global__ void k_gather(const int* __restrict__ col, const int* __restrict__ offs,
                         const int* __restrict__ cnt, const float* __restrict__ asrc,
                         const float* __restrict__ adst, const __half2* __restrict__ h2,
                         const float* __restrict__ bias, float* __restrict__ out, int N) {
    int t = blockIdx.x * 256 + threadIdx.x;
    int n = t >> 6;
    if (n >= N) return;
    const int lane = t & 63;
    const int g  = lane >> 4;    // edge group 0..3
    const int c2 = lane & 15;    // half2 channel pair
    const float adst_n = adst[n];
    float l = 0.0f, accx = 0.0f, accy = 0.0f;
    if (g == 0) {                // self loop
        float p = __expf(leaky(asrc[n] + adst_n));
        float2 hv = __half22float2(h2[(size_t)n * 16 + c2]);
        l = p; accx = p * hv.x; accy = p * hv.y;
    }
    const int off = offs[n];
    const int deg = cnt[n];
    const int q = (deg + 3) >> 2;            // quarter size
    int j = off + g * q;
    const int jend = min(j + q, off + deg);
    for (; j < jend; j += 4) {
        const int last = jend - 1;
        int i1 = min(j + 1, last), i2 = min(j + 2, last), i3 = min(j + 3, last);
        int s0 = col[j], s1 = col[i1], s2 = col[i2], s3 = col[i3];
        float a0 = asrc[s0], a1 = asrc[s1], a2 = asrc[s2], a3 = asrc[s3];
        float2 h0 = __half22float2(h2[(size_t)s0 * 16 + c2]);
        float2 h1 = __half22float2(h2[(size_t)s1 * 16 + c2]);
        float2 hv2 = __half22float2(h2[(size_t)s2 * 16 + c2]);
        float2 h3 = __half22float2(h2[(size_t)s3 * 16 + c2]);
        float p0 = __expf(leaky(a0 + adst_n));
        float p1 = (j + 1 < jend) ? __expf(leaky(a1 + adst_n)) : 0.0f;
        float p2 = (j + 2 < jend) ? __expf(leaky(a2 + adst_n)) : 0.0f;
        float p3 = (j + 3 < jend) ? __expf(leaky(a3 + adst_n)) : 0.0f;
        l += (p0 + p1) + (p2 + p3);
        accx += p0 * h0.x + p1 * h1.x + p2 * hv2.x + p3 * h3.x;
        accy += p0 * h0.y + p1 * h1.y + p2 * hv2.y + p3 * h3.y;
    }
    l    += __shfl_xor(l, 16);    l    += __shfl_xor(l, 32);
    accx += __shfl_xor(accx, 16); accx += __shfl_xor(accx, 32);
    accy += __shfl_xor(accy, 16); accy += __shfl_xor(accy, 32);
    if (g == 0) {
        float inv = 1.0f / l;
        float2 bb = ((const float2*)bias)[c2];
        float2 o;
        o.x = fmaxf(accx * inv + bb.x, 0.0f);
        o.y = fmaxf(accy * inv + bb.y, 0.0f);
        ((float2*)out)[(size_t)n * 16 + c2] = o;
    }
}

extern "C" void kernel_launch(void* const* d_in, const int* in_sizes, int n_in,
                              void* d_out, int out_size, void* d_ws, size_t ws_size,
                              hipStream_t stream) {
    const float* x        = (const float*)d_in[0];
    const int*   eidx     = (const int*)d_in[1];   // [2, E] flat int32
    const float* W        = (const float*)d_in[2];
    const float* att_src  = (const float*)d_in[3];
    const float* att_dst  = (const float*)d_in[4];
    const float* bias     = (const float*)d_in[5];
    float* out = (float*)d_out;

    const int N = in_sizes[0] / IN_F;
    const int E = in_sizes[1] / 2;
    const int* src = eidx;
    const int* dst = eidx + E;

    const int NB  = (N + BK - 1) >> BK_SHIFT;    // 782 buckets
    const int epb = (E + NBLKA - 1) / NBLKA;     // edges per hist/bpart block

    // Workspace (4 B elems, ~21.9 MB)
    int* u = (int*)d_ws;
    size_t o = 0;
    __half2* h2   = (__half2*)(u + o); o += (size_t)N * 16;   // N*16 half2
    float*   asrc = (float*)(u + o);   o += N;
    float*   adst = (float*)(u + o);   o += N;
    int*     cnt  = u + o;             o += N;
    int*     offs = u + o;             o += N;
    int*     hist = u + o;             o += (size_t)NB * NBLKA;  // ~200k
    int*     bsum = u + o;             o += NBMAX;
    int*     col  = u + o;             o += E;
    int*     recs = u + o;             o += E;

    const int PB = (N + 63) / 64;                // MFMA proj blocks (64 nodes/block)
    const int gatherBlocks = ((size_t)N * 64 + 255) / 256;

    k_projhist<<<PB + NBLKA, 256, 0, stream>>>(x, W, att_src, att_dst, h2, asrc, adst,
                                               dst, hist, N, NB, E, epb, PB);
    k_scan1<<<NB, 256, 0, stream>>>(hist, bsum, NB);
    k_bpart<<<NBLKA, 512, 0, stream>>>(src, dst, hist, bsum, recs, NB, E, epb);
    k_place<<<NB, 256, 0, stream>>>(recs, bsum, cnt, offs, col, NB, E, N);
    k_gather<<<gatherBlocks, 256, 0, stream>>>(col, offs, cnt, asrc, adst, h2, bias, out, N);
}